// Round 4
// baseline (1847.614 us; speedup 1.0000x reference)
//
#include <hip/hip_runtime.h>
#include <hip/hip_bf16.h>
#include <math.h>

#define B_ 16
#define T_ 64
#define C_ 64
#define W_ 256
#define H_ 128
#define CH_ 192   // C_ + H_
#define K_ 5

#define OUT_SEQ_ELEMS ((size_t)B_ * T_ * H_ * W_)            // 33,554,432
#define OUT_H_OFF     OUT_SEQ_ELEMS                          // final h [B,H,W]
#define OUT_C_OFF     (OUT_SEQ_ELEMS + (size_t)B_ * H_ * W_) // final c [B,H,W]

// ---- workspace layout (bytes) ----
#define WS_WF_OFF  0                              // Wfrag bf16: 960*64*8 el = 983040 B
#define WS_XT_OFF  (983040)                       // xT bf16 [B][T][W][C] = 33554432 B
#define WS_HT_OFF  (WS_XT_OFF + 33554432)         // 2 x hT bf16 [B][W][H] = 1 MB each
#define HT_ELEMS   ((size_t)B_ * W_ * H_)
#define WS_CNT_OFF (WS_HT_OFF + 2 * 1048576)      // 16 padded counters (64B stride)

typedef __attribute__((ext_vector_type(8))) short bf16x8;
typedef __attribute__((ext_vector_type(4))) float f32x4;
typedef __attribute__((ext_vector_type(4))) unsigned int u32x4;

__device__ __forceinline__ float sigmoid_f(float x) {
    return 1.0f / (1.0f + __expf(-x));
}
__device__ __forceinline__ float tanh_f(float x) {
    return 1.0f - 2.0f / (__expf(2.0f * x) + 1.0f);
}

// ---------- prep: weights -> MFMA fragment-major bf16 ----------
// frag f = ((ht*4 + g)*5 + ktap)*6 + chunk ; element [f][lane][j]
// value = Wc[g*128 + ht*16 + (lane&15)][chunk*32 + 8*(lane>>4) + j][ktap]
__global__ __launch_bounds__(256)
void prep_wfrag(const float* __restrict__ Wc, __hip_bfloat16* __restrict__ wf) {
    int idx = blockIdx.x * 256 + threadIdx.x;
    if (idx >= 960 * 64) return;
    int lane  = idx & 63;
    int f     = idx >> 6;
    int chunk = f % 6;
    int ktap  = (f / 6) % 5;
    int g     = (f / 30) % 4;
    int ht    = f / 120;
    int chan  = g * 128 + ht * 16 + (lane & 15);
    int ci0   = chunk * 32 + 8 * (lane >> 4);
    __hip_bfloat16 tmp[8];
#pragma unroll
    for (int j = 0; j < 8; ++j)
        tmp[j] = __float2bfloat16(Wc[((size_t)chan * CH_ + (ci0 + j)) * K_ + ktap]);
    *reinterpret_cast<u32x4*>(&wf[(size_t)idx * 8]) = *reinterpret_cast<const u32x4*>(tmp);
}

// ---------- prep: x [B,T,C,W] f32 -> xT [B,T,W,C] bf16 ----------
__global__ __launch_bounds__(256)
void prep_xt(const float* __restrict__ x, __hip_bfloat16* __restrict__ xt) {
    __shared__ float tile[64][65];
    int bt = blockIdx.x;
    int w0 = blockIdx.y * 64;
    const float* src = x + (size_t)bt * C_ * W_ + w0;
#pragma unroll
    for (int i = 0; i < 16; ++i) {
        int idx = i * 256 + threadIdx.x;
        int ci = idx >> 6, wr = idx & 63;
        tile[ci][wr] = src[(size_t)ci * W_ + wr];
    }
    __syncthreads();
    __hip_bfloat16* dst = xt + ((size_t)bt * W_ + w0) * C_;
#pragma unroll
    for (int i = 0; i < 8; ++i) {
        int idx = i * 256 + threadIdx.x;
        int wr = idx >> 5, cp = (idx & 31) * 2;
        __hip_bfloat16 a = __float2bfloat16(tile[cp][wr]);
        __hip_bfloat16 b = __float2bfloat16(tile[cp + 1][wr]);
        ushort2 v;
        v.x = *reinterpret_cast<unsigned short*>(&a);
        v.y = *reinterpret_cast<unsigned short*>(&b);
        *reinterpret_cast<ushort2*>(&dst[(size_t)wr * C_ + cp]) = v;
    }
}

__global__ void init_cnt(unsigned int* cnt) {
    if (threadIdx.x < 16 * 16) cnt[threadIdx.x] = 0;
}

// ---------- persistent kernel: all 64 steps ----------
// Regular launch (NOT cooperative). Co-residency guaranteed by capacity:
// 4 waves + 50688B LDS + <=512 VGPR per block -> >=2 blocks/CU worst case
// -> 256 blocks always fit on 256 CUs; counter protocol cannot deadlock.
#define PITCH_B 384   // bytes per combT row (192 ci * 2B), XOR-swizzled
#define NROWS   132   // 128 positions + 4 halo

__global__ __launch_bounds__(256, 1)
void lstm_persistent(const __hip_bfloat16* __restrict__ xt,
                     const __hip_bfloat16* __restrict__ wf,
                     const float* __restrict__ bc,
                     __hip_bfloat16* __restrict__ hbuf0,
                     __hip_bfloat16* __restrict__ hbuf1,
                     float* __restrict__ out,
                     unsigned int* __restrict__ cnt)
{
    __shared__ char lds[50688];          // combT 132*384 ; reused for gbuf(32K)+hbf(6K)
    const int ht   = blockIdx.x;         // 0..7
    const int wseg = blockIdx.y;         // 0..1
    const int b    = blockIdx.z;         // 0..15
    const int tid  = threadIdx.x;
    const int lane = tid & 63;
    const int g    = tid >> 6;           // wave id == gate
    const int l15  = lane & 15;
    const int lg   = lane >> 4;
    unsigned int* cntb = cnt + b * 16;   // padded counter for this batch

    // ---- persistent state: weights in VGPRs, bias, c-state ----
    bf16x8 wreg[30];
    {
        const __hip_bfloat16* wfbase = wf + (size_t)(ht * 4 + g) * 30 * 512 + (size_t)lane * 8;
#pragma unroll
        for (int f = 0; f < 30; ++f)
            wreg[f] = *reinterpret_cast<const bf16x8*>(wfbase + (size_t)f * 512);
    }
    float bias[4];
    {
        int chanbase = g * 128 + ht * 16 + (lg << 2);
#pragma unroll
        for (int r = 0; r < 4; ++r) bias[r] = bc[chanbase + r];
    }
    float cstate[8];
#pragma unroll
    for (int i = 0; i < 8; ++i) cstate[i] = 0.0f;

    const int wbase = wseg * 128 - 2;
    const int cib = 16 * lg;

    for (int t = 0; t < T_; ++t) {
        // ---- wait for h(t-1) from all 16 blocks of this batch ----
        if (t > 0) {
            if (tid == 0) {
                unsigned int target = 16u * (unsigned int)t;
                while (__hip_atomic_load(cntb, __ATOMIC_RELAXED, __HIP_MEMORY_SCOPE_AGENT) < target)
                    __builtin_amdgcn_s_sleep(2);
                __threadfence();   // acquire: invalidate L1/L2 before reading remote hT
            }
        }
        __syncthreads();

        const __hip_bfloat16* xrow = xt + ((size_t)(b * T_ + t) * W_) * C_;
        const __hip_bfloat16* hrow = ((t & 1) ? hbuf0 : hbuf1) + (size_t)b * W_ * H_;
        __hip_bfloat16* hout = ((t & 1) ? hbuf1 : hbuf0);

        // ---- stage combT tile (x + h, zero h at t==0), XOR swizzle ----
        for (int idx = tid; idx < NROWS * 24; idx += 256) {
            int wrel = idx / 24;
            int c16  = idx % 24;
            int w = wbase + wrel;
            u32x4 v = {0u, 0u, 0u, 0u};
            if (w >= 0 && w < W_) {
                if (c16 < 8)      v = *reinterpret_cast<const u32x4*>(xrow + (size_t)w * C_ + c16 * 8);
                else if (t > 0)   v = *reinterpret_cast<const u32x4*>(hrow + (size_t)w * H_ + (c16 - 8) * 8);
            }
            int byteoff = wrel * PITCH_B + ((c16 * 16) ^ ((wrel & 7) << 4));
            *reinterpret_cast<u32x4*>(lds + byteoff) = v;
        }
        __syncthreads();

        // ---- MFMA: 6 chunks x 5 taps x 8 n-frags, weights from regs ----
        f32x4 acc[8];
#pragma unroll
        for (int nf = 0; nf < 8; ++nf) {
            acc[nf][0] = bias[0]; acc[nf][1] = bias[1];
            acc[nf][2] = bias[2]; acc[nf][3] = bias[3];
        }
#pragma unroll
        for (int c = 0; c < 6; ++c) {
#pragma unroll
            for (int k = 0; k < K_; ++k) {
                bf16x8 afrag = wreg[k * 6 + c];
#pragma unroll
                for (int nf = 0; nf < 8; ++nf) {
                    int wrel = nf * 16 + l15 + k;
                    int byteoff = wrel * PITCH_B + ((c * 64 + cib) ^ ((wrel & 7) << 4));
                    bf16x8 bfrag = *reinterpret_cast<const bf16x8*>(lds + byteoff);
                    acc[nf] = __builtin_amdgcn_mfma_f32_16x16x32_bf16(afrag, bfrag, acc[nf], 0, 0, 0);
                }
            }
        }

        // ---- exchange gates through LDS ----
        __syncthreads();
        float* gbuf = reinterpret_cast<float*>(lds);   // [4][16][128] f32
        {
            int rowb = lg << 2;
#pragma unroll
            for (int nf = 0; nf < 8; ++nf)
#pragma unroll
                for (int r = 0; r < 4; ++r)
                    gbuf[(g * 16 + rowb + r) * 128 + nf * 16 + l15] = acc[nf][r];
        }
        __syncthreads();

        // ---- gating: c in registers; write h (fp32 out + bf16 LDS) ----
        __hip_bfloat16* hbf = reinterpret_cast<__hip_bfloat16*>(lds + 32768); // [128][pitch 24]
        float* hw = out + ((size_t)(b * T_ + t) * H_ + ht * 16) * W_ + wseg * 128;

#pragma unroll
        for (int i = 0; i < 8; ++i) {
            int idx  = i * 256 + tid;
            int chan = idx >> 7;
            int pos  = idx & 127;
            float vi = gbuf[(0 * 16 + chan) * 128 + pos];
            float vf = gbuf[(1 * 16 + chan) * 128 + pos];
            float vo = gbuf[(2 * 16 + chan) * 128 + pos];
            float vg = gbuf[(3 * 16 + chan) * 128 + pos];
            float ii = sigmoid_f(vi), ff = sigmoid_f(vf), oo = sigmoid_f(vo), gg = tanh_f(vg);
            float cn = ff * cstate[i] + ii * gg;
            cstate[i] = cn;
            float hn = oo * tanh_f(cn);
            hw[(size_t)chan * W_ + pos] = hn;
            hbf[pos * 24 + chan] = __float2bfloat16(hn);
            if (t == T_ - 1) {
                out[OUT_H_OFF + ((size_t)b * H_ + ht * 16 + chan) * W_ + wseg * 128 + pos] = hn;
                out[OUT_C_OFF + ((size_t)b * H_ + ht * 16 + chan) * W_ + wseg * 128 + pos] = cn;
            }
        }
        __syncthreads();

        // ---- publish hT bf16 [b][w][ci] for next step ----
        {
            int w = tid >> 1, grp = tid & 1;
            u32x4 v = *reinterpret_cast<const u32x4*>(lds + 32768 + w * 48 + grp * 16);
            *reinterpret_cast<u32x4*>(hout + ((size_t)b * W_ + wseg * 128 + w) * H_ + ht * 16 + grp * 8) = v;
        }
        __syncthreads();   // drains vmcnt: all waves' hT stores complete before signal
        if (tid == 0)
            __hip_atomic_fetch_add(cntb, 1u, __ATOMIC_RELEASE, __HIP_MEMORY_SCOPE_AGENT);
    }
}

extern "C" void kernel_launch(void* const* d_in, const int* in_sizes, int n_in,
                              void* d_out, int out_size, void* d_ws, size_t ws_size,
                              hipStream_t stream)
{
    const float* x  = (const float*)d_in[0];
    const float* Wc = (const float*)d_in[1];
    const float* bc = (const float*)d_in[2];
    float* out = (float*)d_out;
    char*  ws  = (char*)d_ws;

    __hip_bfloat16* wf  = (__hip_bfloat16*)(ws + WS_WF_OFF);
    __hip_bfloat16* xt  = (__hip_bfloat16*)(ws + WS_XT_OFF);
    __hip_bfloat16* hb0 = (__hip_bfloat16*)(ws + WS_HT_OFF);
    __hip_bfloat16* hb1 = (__hip_bfloat16*)(ws + WS_HT_OFF + 1048576);
    unsigned int*   cnt = (unsigned int*)(ws + WS_CNT_OFF);

    prep_wfrag<<<240, 256, 0, stream>>>(Wc, wf);
    prep_xt<<<dim3(B_ * T_, 4), 256, 0, stream>>>(x, xt);
    init_cnt<<<1, 256, 0, stream>>>(cnt);

    lstm_persistent<<<dim3(8, 2, B_), 256, 0, stream>>>(xt, wf, bc, hb0, hb1, out, cnt);
}

// Round 5
// 988.073 us; speedup vs baseline: 1.8699x; 1.8699x over previous
//
#include <hip/hip_runtime.h>
#include <hip/hip_bf16.h>
#include <math.h>

#define B_ 16
#define T_ 64
#define C_ 64
#define W_ 256
#define H_ 128
#define CH_ 192   // C_ + H_
#define K_ 5

#define OUT_SEQ_ELEMS ((size_t)B_ * T_ * H_ * W_)            // 33,554,432
#define OUT_H_OFF     OUT_SEQ_ELEMS                          // final h [B,H,W]
#define OUT_C_OFF     (OUT_SEQ_ELEMS + (size_t)B_ * H_ * W_) // final c [B,H,W]

// ---- workspace layout (bytes) ----
#define WS_WF_OFF  0                              // Wfrag bf16: 960*64*8 el = 983040 B
#define WS_XT_OFF  (983040)                       // xT bf16 [B][T][W][C] = 33554432 B
#define WS_HT_OFF  (WS_XT_OFF + 33554432)         // 2 x hT bf16 [B][W][H] = 1 MB each
#define WS_CNT_OFF (WS_HT_OFF + 2 * 1048576)      // 16 padded counters (64B stride)

typedef __attribute__((ext_vector_type(8))) short bf16x8;
typedef __attribute__((ext_vector_type(4))) float f32x4;
typedef __attribute__((ext_vector_type(4))) unsigned int u32x4;

__device__ __forceinline__ float sigmoid_f(float x) {
    return 1.0f / (1.0f + __expf(-x));
}
__device__ __forceinline__ float tanh_f(float x) {
    return 1.0f - 2.0f / (__expf(2.0f * x) + 1.0f);
}

// ---------- prep: weights -> MFMA fragment-major bf16 ----------
__global__ __launch_bounds__(256)
void prep_wfrag(const float* __restrict__ Wc, __hip_bfloat16* __restrict__ wf) {
    int idx = blockIdx.x * 256 + threadIdx.x;
    if (idx >= 960 * 64) return;
    int lane  = idx & 63;
    int f     = idx >> 6;
    int chunk = f % 6;
    int ktap  = (f / 6) % 5;
    int g     = (f / 30) % 4;
    int ht    = f / 120;
    int chan  = g * 128 + ht * 16 + (lane & 15);
    int ci0   = chunk * 32 + 8 * (lane >> 4);
    __hip_bfloat16 tmp[8];
#pragma unroll
    for (int j = 0; j < 8; ++j)
        tmp[j] = __float2bfloat16(Wc[((size_t)chan * CH_ + (ci0 + j)) * K_ + ktap]);
    *reinterpret_cast<u32x4*>(&wf[(size_t)idx * 8]) = *reinterpret_cast<const u32x4*>(tmp);
}

// ---------- prep: x [B,T,C,W] f32 -> xT [B,T,W,C] bf16 ----------
__global__ __launch_bounds__(256)
void prep_xt(const float* __restrict__ x, __hip_bfloat16* __restrict__ xt) {
    __shared__ float tile[64][65];
    int bt = blockIdx.x;
    int w0 = blockIdx.y * 64;
    const float* src = x + (size_t)bt * C_ * W_ + w0;
#pragma unroll
    for (int i = 0; i < 16; ++i) {
        int idx = i * 256 + threadIdx.x;
        int ci = idx >> 6, wr = idx & 63;
        tile[ci][wr] = src[(size_t)ci * W_ + wr];
    }
    __syncthreads();
    __hip_bfloat16* dst = xt + ((size_t)bt * W_ + w0) * C_;
#pragma unroll
    for (int i = 0; i < 8; ++i) {
        int idx = i * 256 + threadIdx.x;
        int wr = idx >> 5, cp = (idx & 31) * 2;
        __hip_bfloat16 a = __float2bfloat16(tile[cp][wr]);
        __hip_bfloat16 b = __float2bfloat16(tile[cp + 1][wr]);
        ushort2 v;
        v.x = *reinterpret_cast<unsigned short*>(&a);
        v.y = *reinterpret_cast<unsigned short*>(&b);
        *reinterpret_cast<ushort2*>(&dst[(size_t)wr * C_ + cp]) = v;
    }
}

__global__ void init_cnt(unsigned int* cnt) {
    if (threadIdx.x < 16 * 16) cnt[threadIdx.x] = 0;
}

// ---------- persistent kernel: all 64 steps ----------
// Regular launch; 256 blocks (4 waves, 50688B LDS, <=512 VGPR) always co-resident.
// Cross-block h/counter traffic goes through the coherent memory-side LLC via
// RELAXED AGENT-scope atomics (global_load/store sc1) -- NO buffer_wbl2 /
// buffer_inv cache flushes (round-4 regression cause). xT stays hot in L2.
#define PITCH_B 384   // bytes per combT row (192 ci * 2B), XOR-swizzled
#define NROWS   132   // 128 positions + 4 halo

__global__ __launch_bounds__(256, 1)
void lstm_persistent(const __hip_bfloat16* __restrict__ xt,
                     const __hip_bfloat16* __restrict__ wf,
                     const float* __restrict__ bc,
                     __hip_bfloat16* __restrict__ hbuf0,
                     __hip_bfloat16* __restrict__ hbuf1,
                     float* __restrict__ out,
                     unsigned int* __restrict__ cnt)
{
    __shared__ char lds[50688];          // combT 132*384 ; reused for gbuf(32K)+hbf(6K)
    const int ht   = blockIdx.x;         // 0..7
    const int wseg = blockIdx.y;         // 0..1
    const int b    = blockIdx.z;         // 0..15
    const int tid  = threadIdx.x;
    const int lane = tid & 63;
    const int g    = tid >> 6;           // wave id == gate
    const int l15  = lane & 15;
    const int lg   = lane >> 4;
    unsigned int* cntb = cnt + b * 16;   // padded counter for this batch

    // ---- persistent state: weights in VGPRs, bias, c-state ----
    bf16x8 wreg[30];
    {
        const __hip_bfloat16* wfbase = wf + (size_t)(ht * 4 + g) * 30 * 512 + (size_t)lane * 8;
#pragma unroll
        for (int f = 0; f < 30; ++f)
            wreg[f] = *reinterpret_cast<const bf16x8*>(wfbase + (size_t)f * 512);
    }
    float bias[4];
    {
        int chanbase = g * 128 + ht * 16 + (lg << 2);
#pragma unroll
        for (int r = 0; r < 4; ++r) bias[r] = bc[chanbase + r];
    }
    float cstate[8];
#pragma unroll
    for (int i = 0; i < 8; ++i) cstate[i] = 0.0f;

    const int wbase = wseg * 128 - 2;
    const int cib = 16 * lg;

    for (int t = 0; t < T_; ++t) {
        const __hip_bfloat16* xrow = xt + ((size_t)(b * T_ + t) * W_) * C_;
        const __hip_bfloat16* hrow = ((t & 1) ? hbuf0 : hbuf1) + (size_t)b * W_ * H_;
        __hip_bfloat16* hout = ((t & 1) ? hbuf1 : hbuf0);

        // ---- stage x half of combT (independent of h -> overlaps the wait) ----
        for (int idx = tid; idx < NROWS * 8; idx += 256) {
            int wrel = idx >> 3;
            int c16  = idx & 7;
            int w = wbase + wrel;
            u32x4 v = {0u, 0u, 0u, 0u};
            if (w >= 0 && w < W_)
                v = *reinterpret_cast<const u32x4*>(xrow + (size_t)w * C_ + c16 * 8);
            int byteoff = wrel * PITCH_B + ((c16 * 16) ^ ((wrel & 7) << 4));
            *reinterpret_cast<u32x4*>(lds + byteoff) = v;
        }

        // ---- wait for h(t-1) from all 16 blocks of this batch ----
        if (t > 0) {
            if (tid == 0) {
                unsigned int target = 16u * (unsigned int)t;
                while (__hip_atomic_load(cntb, __ATOMIC_RELAXED, __HIP_MEMORY_SCOPE_AGENT) < target)
                    __builtin_amdgcn_s_sleep(1);
            }
        }
        __syncthreads();
        __atomic_signal_fence(__ATOMIC_SEQ_CST);   // compiler barrier (no ISA cost)

        // ---- stage h half of combT (coherent LLC loads), zero at t==0 ----
        if (t > 0) {
            for (int idx = tid; idx < NROWS * 16; idx += 256) {
                int wrel = idx >> 4;
                int c16  = (idx & 15) + 8;
                int w = wbase + wrel;
                u32x4 v = {0u, 0u, 0u, 0u};
                if (w >= 0 && w < W_) {
                    const unsigned int* hp = reinterpret_cast<const unsigned int*>(
                        hrow + (size_t)w * H_ + (size_t)(c16 - 8) * 8);
                    v[0] = __hip_atomic_load(hp + 0, __ATOMIC_RELAXED, __HIP_MEMORY_SCOPE_AGENT);
                    v[1] = __hip_atomic_load(hp + 1, __ATOMIC_RELAXED, __HIP_MEMORY_SCOPE_AGENT);
                    v[2] = __hip_atomic_load(hp + 2, __ATOMIC_RELAXED, __HIP_MEMORY_SCOPE_AGENT);
                    v[3] = __hip_atomic_load(hp + 3, __ATOMIC_RELAXED, __HIP_MEMORY_SCOPE_AGENT);
                }
                int byteoff = wrel * PITCH_B + ((c16 * 16) ^ ((wrel & 7) << 4));
                *reinterpret_cast<u32x4*>(lds + byteoff) = v;
            }
        } else {
            for (int idx = tid; idx < NROWS * 16; idx += 256) {
                int wrel = idx >> 4;
                int c16  = (idx & 15) + 8;
                int byteoff = wrel * PITCH_B + ((c16 * 16) ^ ((wrel & 7) << 4));
                u32x4 z = {0u, 0u, 0u, 0u};
                *reinterpret_cast<u32x4*>(lds + byteoff) = z;
            }
        }
        __syncthreads();

        // ---- MFMA: 6 chunks x 5 taps x 8 n-frags, weights from regs ----
        f32x4 acc[8];
#pragma unroll
        for (int nf = 0; nf < 8; ++nf) {
            acc[nf][0] = bias[0]; acc[nf][1] = bias[1];
            acc[nf][2] = bias[2]; acc[nf][3] = bias[3];
        }
#pragma unroll
        for (int c = 0; c < 6; ++c) {
#pragma unroll
            for (int k = 0; k < K_; ++k) {
                bf16x8 afrag = wreg[k * 6 + c];
#pragma unroll
                for (int nf = 0; nf < 8; ++nf) {
                    int wrel = nf * 16 + l15 + k;
                    int byteoff = wrel * PITCH_B + ((c * 64 + cib) ^ ((wrel & 7) << 4));
                    bf16x8 bfrag = *reinterpret_cast<const bf16x8*>(lds + byteoff);
                    acc[nf] = __builtin_amdgcn_mfma_f32_16x16x32_bf16(afrag, bfrag, acc[nf], 0, 0, 0);
                }
            }
        }

        // ---- exchange gates through LDS ----
        __syncthreads();
        float* gbuf = reinterpret_cast<float*>(lds);   // [4][16][128] f32
        {
            int rowb = lg << 2;
#pragma unroll
            for (int nf = 0; nf < 8; ++nf)
#pragma unroll
                for (int r = 0; r < 4; ++r)
                    gbuf[(g * 16 + rowb + r) * 128 + nf * 16 + l15] = acc[nf][r];
        }
        __syncthreads();

        // ---- gating: c in registers; write h (fp32 out + bf16 LDS) ----
        __hip_bfloat16* hbf = reinterpret_cast<__hip_bfloat16*>(lds + 32768); // [128][pitch 24]
        float* hw = out + ((size_t)(b * T_ + t) * H_ + ht * 16) * W_ + wseg * 128;

#pragma unroll
        for (int i = 0; i < 8; ++i) {
            int idx  = i * 256 + tid;
            int chan = idx >> 7;
            int pos  = idx & 127;
            float vi = gbuf[(0 * 16 + chan) * 128 + pos];
            float vf = gbuf[(1 * 16 + chan) * 128 + pos];
            float vo = gbuf[(2 * 16 + chan) * 128 + pos];
            float vg = gbuf[(3 * 16 + chan) * 128 + pos];
            float ii = sigmoid_f(vi), ff = sigmoid_f(vf), oo = sigmoid_f(vo), gg = tanh_f(vg);
            float cn = ff * cstate[i] + ii * gg;
            cstate[i] = cn;
            float hn = oo * tanh_f(cn);
            hw[(size_t)chan * W_ + pos] = hn;
            hbf[pos * 24 + chan] = __float2bfloat16(hn);
            if (t == T_ - 1) {
                out[OUT_H_OFF + ((size_t)b * H_ + ht * 16 + chan) * W_ + wseg * 128 + pos] = hn;
                out[OUT_C_OFF + ((size_t)b * H_ + ht * 16 + chan) * W_ + wseg * 128 + pos] = cn;
            }
        }
        __syncthreads();

        // ---- publish hT bf16 [b][w][ci] via coherent LLC stores ----
        {
            int w = tid >> 1, grp = tid & 1;
            u32x4 v = *reinterpret_cast<const u32x4*>(lds + 32768 + w * 48 + grp * 16);
            unsigned int* hp = reinterpret_cast<unsigned int*>(
                hout + ((size_t)b * W_ + wseg * 128 + w) * H_ + ht * 16 + grp * 8);
            __hip_atomic_store(hp + 0, v[0], __ATOMIC_RELAXED, __HIP_MEMORY_SCOPE_AGENT);
            __hip_atomic_store(hp + 1, v[1], __ATOMIC_RELAXED, __HIP_MEMORY_SCOPE_AGENT);
            __hip_atomic_store(hp + 2, v[2], __ATOMIC_RELAXED, __HIP_MEMORY_SCOPE_AGENT);
            __hip_atomic_store(hp + 3, v[3], __ATOMIC_RELAXED, __HIP_MEMORY_SCOPE_AGENT);
        }
        __syncthreads();   // vmcnt(0): all waves' LLC stores have landed before signal
        if (tid == 0)
            __hip_atomic_fetch_add(cntb, 1u, __ATOMIC_RELAXED, __HIP_MEMORY_SCOPE_AGENT);
    }
}

extern "C" void kernel_launch(void* const* d_in, const int* in_sizes, int n_in,
                              void* d_out, int out_size, void* d_ws, size_t ws_size,
                              hipStream_t stream)
{
    const float* x  = (const float*)d_in[0];
    const float* Wc = (const float*)d_in[1];
    const float* bc = (const float*)d_in[2];
    float* out = (float*)d_out;
    char*  ws  = (char*)d_ws;

    __hip_bfloat16* wf  = (__hip_bfloat16*)(ws + WS_WF_OFF);
    __hip_bfloat16* xt  = (__hip_bfloat16*)(ws + WS_XT_OFF);
    __hip_bfloat16* hb0 = (__hip_bfloat16*)(ws + WS_HT_OFF);
    __hip_bfloat16* hb1 = (__hip_bfloat16*)(ws + WS_HT_OFF + 1048576);
    unsigned int*   cnt = (unsigned int*)(ws + WS_CNT_OFF);

    prep_wfrag<<<240, 256, 0, stream>>>(Wc, wf);
    prep_xt<<<dim3(B_ * T_, 4), 256, 0, stream>>>(x, xt);
    init_cnt<<<1, 256, 0, stream>>>(cnt);

    lstm_persistent<<<dim3(8, 2, B_), 256, 0, stream>>>(xt, wf, bc, hb0, hb1, out, cnt);
}

// Round 6
// 800.202 us; speedup vs baseline: 2.3089x; 1.2348x over previous
//
#include <hip/hip_runtime.h>
#include <hip/hip_bf16.h>
#include <math.h>

#define B_ 16
#define T_ 64
#define C_ 64
#define W_ 256
#define H_ 128
#define CH_ 192   // C_ + H_
#define K_ 5

#define OUT_SEQ_ELEMS ((size_t)B_ * T_ * H_ * W_)            // 33,554,432
#define OUT_H_OFF     OUT_SEQ_ELEMS                          // final h [B,H,W]
#define OUT_C_OFF     (OUT_SEQ_ELEMS + (size_t)B_ * H_ * W_) // final c [B,H,W]

// ---- workspace layout (bytes) ----
#define WS_WF_OFF  0                              // Wfrag bf16: 983040 B
#define WS_XT_OFF  (983040)                       // xT bf16 [B][T][W][C] = 33554432 B
#define WS_HT_OFF  (WS_XT_OFF + 33554432)         // 2 x hT bf16 [B][W][H] = 1 MB each
#define WS_CNT_OFF (WS_HT_OFF + 2 * 1048576)      // 16 padded counters (64B stride)

typedef __attribute__((ext_vector_type(8))) short bf16x8;
typedef __attribute__((ext_vector_type(4))) float f32x4;
typedef __attribute__((ext_vector_type(4))) unsigned int u32x4;

__device__ __forceinline__ float sigmoid_f(float x) {
    return 1.0f / (1.0f + __expf(-x));
}
__device__ __forceinline__ float tanh_f(float x) {
    return 1.0f - 2.0f / (__expf(2.0f * x) + 1.0f);
}

// ---------- prep: weights -> MFMA fragment-major bf16 ----------
__global__ __launch_bounds__(256)
void prep_wfrag(const float* __restrict__ Wc, __hip_bfloat16* __restrict__ wf) {
    int idx = blockIdx.x * 256 + threadIdx.x;
    if (idx >= 960 * 64) return;
    int lane  = idx & 63;
    int f     = idx >> 6;
    int chunk = f % 6;
    int ktap  = (f / 6) % 5;
    int g     = (f / 30) % 4;
    int ht    = f / 120;
    int chan  = g * 128 + ht * 16 + (lane & 15);
    int ci0   = chunk * 32 + 8 * (lane >> 4);
    __hip_bfloat16 tmp[8];
#pragma unroll
    for (int j = 0; j < 8; ++j)
        tmp[j] = __float2bfloat16(Wc[((size_t)chan * CH_ + (ci0 + j)) * K_ + ktap]);
    *reinterpret_cast<u32x4*>(&wf[(size_t)idx * 8]) = *reinterpret_cast<const u32x4*>(tmp);
}

// ---------- prep: x [B,T,C,W] f32 -> xT [B,T,W,C] bf16 ----------
__global__ __launch_bounds__(256)
void prep_xt(const float* __restrict__ x, __hip_bfloat16* __restrict__ xt) {
    __shared__ float tile[64][65];
    int bt = blockIdx.x;
    int w0 = blockIdx.y * 64;
    const float* src = x + (size_t)bt * C_ * W_ + w0;
#pragma unroll
    for (int i = 0; i < 16; ++i) {
        int idx = i * 256 + threadIdx.x;
        int ci = idx >> 6, wr = idx & 63;
        tile[ci][wr] = src[(size_t)ci * W_ + wr];
    }
    __syncthreads();
    __hip_bfloat16* dst = xt + ((size_t)bt * W_ + w0) * C_;
#pragma unroll
    for (int i = 0; i < 8; ++i) {
        int idx = i * 256 + threadIdx.x;
        int wr = idx >> 5, cp = (idx & 31) * 2;
        __hip_bfloat16 a = __float2bfloat16(tile[cp][wr]);
        __hip_bfloat16 b = __float2bfloat16(tile[cp + 1][wr]);
        ushort2 v;
        v.x = *reinterpret_cast<unsigned short*>(&a);
        v.y = *reinterpret_cast<unsigned short*>(&b);
        *reinterpret_cast<ushort2*>(&dst[(size_t)wr * C_ + cp]) = v;
    }
}

__global__ void init_cnt(unsigned int* cnt) {
    if (threadIdx.x < 16 * 16) cnt[threadIdx.x] = 0;
}

// ---------- persistent kernel: all 64 steps ----------
// 256 blocks, 1/CU, always co-resident. h/counter traffic via coherent LLC:
// inline-asm global_{load,store}_dwordx4 sc1 (same coherence path LLVM emits
// for agent-relaxed atomics -- verified correct in round 5 -- but 16B/issue).
// Epilogue reordered: hT publish + signal BEFORE fp32 out writes (deferred
// writes use registers only, so no LDS reuse race with next step's staging).
#define PITCH_B 384   // bytes per combT row (192 ci * 2B), XOR-swizzled
#define NROWS   132   // 128 positions + 4 halo

__global__ __launch_bounds__(256, 1)
void lstm_persistent(const __hip_bfloat16* __restrict__ xt,
                     const __hip_bfloat16* __restrict__ wf,
                     const float* __restrict__ bc,
                     __hip_bfloat16* __restrict__ hbuf0,
                     __hip_bfloat16* __restrict__ hbuf1,
                     float* __restrict__ out,
                     unsigned int* __restrict__ cnt)
{
    __shared__ char lds[50688];          // combT 132*384 ; reused for gbuf(32K)+hbf(6K)
    const int ht   = blockIdx.x;         // 0..7
    const int wseg = blockIdx.y;         // 0..1
    const int b    = blockIdx.z;         // 0..15
    const int tid  = threadIdx.x;
    const int lane = tid & 63;
    const int g    = tid >> 6;           // wave id == gate
    const int l15  = lane & 15;
    const int lg   = lane >> 4;
    unsigned int* cntb = cnt + b * 16;   // padded counter for this batch

    // ---- persistent state: weights in VGPRs, bias, c-state ----
    bf16x8 wreg[30];
    {
        const __hip_bfloat16* wfbase = wf + (size_t)(ht * 4 + g) * 30 * 512 + (size_t)lane * 8;
#pragma unroll
        for (int f = 0; f < 30; ++f)
            wreg[f] = *reinterpret_cast<const bf16x8*>(wfbase + (size_t)f * 512);
    }
    float bias[4];
    {
        int chanbase = g * 128 + ht * 16 + (lg << 2);
#pragma unroll
        for (int r = 0; r < 4; ++r) bias[r] = bc[chanbase + r];
    }
    float cstate[8];
#pragma unroll
    for (int i = 0; i < 8; ++i) cstate[i] = 0.0f;

    const int wbase = wseg * 128 - 2;
    const int cib = 16 * lg;

    for (int t = 0; t < T_; ++t) {
        const __hip_bfloat16* xrow = xt + ((size_t)(b * T_ + t) * W_) * C_;
        const __hip_bfloat16* hrow = ((t & 1) ? hbuf0 : hbuf1) + (size_t)b * W_ * H_;
        __hip_bfloat16* hout = ((t & 1) ? hbuf1 : hbuf0);

        // ---- stage x half of combT (independent of h -> overlaps the wait) ----
        for (int idx = tid; idx < NROWS * 8; idx += 256) {
            int wrel = idx >> 3;
            int c16  = idx & 7;
            int w = wbase + wrel;
            u32x4 v = {0u, 0u, 0u, 0u};
            if (w >= 0 && w < W_)
                v = *reinterpret_cast<const u32x4*>(xrow + (size_t)w * C_ + c16 * 8);
            int byteoff = wrel * PITCH_B + ((c16 * 16) ^ ((wrel & 7) << 4));
            *reinterpret_cast<u32x4*>(lds + byteoff) = v;
        }

        // ---- wait for h(t-1) from all 16 blocks of this batch ----
        if (t > 0) {
            if (tid == 0) {
                unsigned int target = 16u * (unsigned int)t;
                while (__hip_atomic_load(cntb, __ATOMIC_RELAXED, __HIP_MEMORY_SCOPE_AGENT) < target)
                    __builtin_amdgcn_s_sleep(1);
            }
        }
        __syncthreads();
        __atomic_signal_fence(__ATOMIC_SEQ_CST);

        // ---- stage h half of combT: dwordx4 sc1 loads (coherent via LLC) ----
        if (t > 0) {
            u32x4 hv[8];
            const u32x4 zz = {0u, 0u, 0u, 0u};
#pragma unroll
            for (int i = 0; i < 8; ++i) {
                int idx  = i * 256 + tid;        // 0..2047
                int wrel = idx >> 4;             // 0..127
                int c16  = idx & 15;             // h-chunk 0..15
                int w = wbase + wrel;
                hv[i] = zz;
                if (w >= 0 && w < W_) {
                    const __hip_bfloat16* hp = hrow + (size_t)w * H_ + c16 * 8;
                    asm volatile("global_load_dwordx4 %0, %1, off sc1"
                                 : "+v"(hv[i]) : "v"(hp));
                }
            }
            u32x4 hv8 = zz;
            if (tid < 64) {                      // tail rows 128..131
                int idx  = 2048 + tid;
                int wrel = idx >> 4;
                int c16  = idx & 15;
                int w = wbase + wrel;
                if (w >= 0 && w < W_) {
                    const __hip_bfloat16* hp = hrow + (size_t)w * H_ + c16 * 8;
                    asm volatile("global_load_dwordx4 %0, %1, off sc1"
                                 : "+v"(hv8) : "v"(hp));
                }
            }
            asm volatile("s_waitcnt vmcnt(0)" ::: "memory");
            __builtin_amdgcn_sched_barrier(0);
#pragma unroll
            for (int i = 0; i < 8; ++i) {
                int idx  = i * 256 + tid;
                int wrel = idx >> 4;
                int c16  = (idx & 15) + 8;
                int byteoff = wrel * PITCH_B + ((c16 * 16) ^ ((wrel & 7) << 4));
                *reinterpret_cast<u32x4*>(lds + byteoff) = hv[i];
            }
            if (tid < 64) {
                int idx  = 2048 + tid;
                int wrel = idx >> 4;
                int c16  = (idx & 15) + 8;
                int byteoff = wrel * PITCH_B + ((c16 * 16) ^ ((wrel & 7) << 4));
                *reinterpret_cast<u32x4*>(lds + byteoff) = hv8;
            }
        } else {
            for (int idx = tid; idx < NROWS * 16; idx += 256) {
                int wrel = idx >> 4;
                int c16  = (idx & 15) + 8;
                int byteoff = wrel * PITCH_B + ((c16 * 16) ^ ((wrel & 7) << 4));
                u32x4 z = {0u, 0u, 0u, 0u};
                *reinterpret_cast<u32x4*>(lds + byteoff) = z;
            }
        }
        __syncthreads();

        // ---- MFMA: 6 chunks x 5 taps x 8 n-frags, weights from regs ----
        f32x4 acc[8];
#pragma unroll
        for (int nf = 0; nf < 8; ++nf) {
            acc[nf][0] = bias[0]; acc[nf][1] = bias[1];
            acc[nf][2] = bias[2]; acc[nf][3] = bias[3];
        }
#pragma unroll
        for (int c = 0; c < 6; ++c) {
#pragma unroll
            for (int k = 0; k < K_; ++k) {
                bf16x8 afrag = wreg[k * 6 + c];
#pragma unroll
                for (int nf = 0; nf < 8; ++nf) {
                    int wrel = nf * 16 + l15 + k;
                    int byteoff = wrel * PITCH_B + ((c * 64 + cib) ^ ((wrel & 7) << 4));
                    bf16x8 bfrag = *reinterpret_cast<const bf16x8*>(lds + byteoff);
                    acc[nf] = __builtin_amdgcn_mfma_f32_16x16x32_bf16(afrag, bfrag, acc[nf], 0, 0, 0);
                }
            }
        }

        // ---- exchange gates through LDS ----
        __syncthreads();
        float* gbuf = reinterpret_cast<float*>(lds);   // [4][16][128] f32
        {
            int rowb = lg << 2;
#pragma unroll
            for (int nf = 0; nf < 8; ++nf)
#pragma unroll
                for (int r = 0; r < 4; ++r)
                    gbuf[(g * 16 + rowb + r) * 128 + nf * 16 + l15] = acc[nf][r];
        }
        __syncthreads();

        // ---- gating: c + h kept in registers; bf16 h -> LDS for publish ----
        __hip_bfloat16* hbf = reinterpret_cast<__hip_bfloat16*>(lds + 32768); // [128][pitch 24]
        float hn_r[8];
#pragma unroll
        for (int i = 0; i < 8; ++i) {
            int idx  = i * 256 + tid;
            int chan = idx >> 7;
            int pos  = idx & 127;
            float vi = gbuf[(0 * 16 + chan) * 128 + pos];
            float vf = gbuf[(1 * 16 + chan) * 128 + pos];
            float vo = gbuf[(2 * 16 + chan) * 128 + pos];
            float vg = gbuf[(3 * 16 + chan) * 128 + pos];
            float ii = sigmoid_f(vi), ff = sigmoid_f(vf), oo = sigmoid_f(vo), gg = tanh_f(vg);
            float cn = ff * cstate[i] + ii * gg;
            cstate[i] = cn;
            float hn = oo * tanh_f(cn);
            hn_r[i] = hn;
            hbf[pos * 24 + chan] = __float2bfloat16(hn);
        }
        __syncthreads();

        // ---- publish hT FIRST (dwordx4 sc1 -> LLC), then signal ----
        {
            int w = tid >> 1, grp = tid & 1;
            u32x4 v = *reinterpret_cast<const u32x4*>(lds + 32768 + w * 48 + grp * 16);
            __hip_bfloat16* hp = hout + ((size_t)b * W_ + wseg * 128 + w) * H_ + ht * 16 + grp * 8;
            asm volatile("global_store_dwordx4 %0, %1, off sc1" :: "v"(hp), "v"(v) : "memory");
        }
        asm volatile("s_waitcnt vmcnt(0)" ::: "memory");   // stores landed at LLC
        __syncthreads();
        if (tid == 0)
            __hip_atomic_fetch_add(cntb, 1u, __ATOMIC_RELAXED, __HIP_MEMORY_SCOPE_AGENT);

        // ---- deferred (off critical path): fp32 out writes from registers ----
        float* hw = out + ((size_t)(b * T_ + t) * H_ + ht * 16) * W_ + wseg * 128;
#pragma unroll
        for (int i = 0; i < 8; ++i) {
            int idx  = i * 256 + tid;
            int chan = idx >> 7;
            int pos  = idx & 127;
            hw[(size_t)chan * W_ + pos] = hn_r[i];
        }
        if (t == T_ - 1) {
#pragma unroll
            for (int i = 0; i < 8; ++i) {
                int idx  = i * 256 + tid;
                int chan = idx >> 7;
                int pos  = idx & 127;
                out[OUT_H_OFF + ((size_t)b * H_ + ht * 16 + chan) * W_ + wseg * 128 + pos] = hn_r[i];
                out[OUT_C_OFF + ((size_t)b * H_ + ht * 16 + chan) * W_ + wseg * 128 + pos] = cstate[i];
            }
        }
    }
}

extern "C" void kernel_launch(void* const* d_in, const int* in_sizes, int n_in,
                              void* d_out, int out_size, void* d_ws, size_t ws_size,
                              hipStream_t stream)
{
    const float* x  = (const float*)d_in[0];
    const float* Wc = (const float*)d_in[1];
    const float* bc = (const float*)d_in[2];
    float* out = (float*)d_out;
    char*  ws  = (char*)d_ws;

    __hip_bfloat16* wf  = (__hip_bfloat16*)(ws + WS_WF_OFF);
    __hip_bfloat16* xt  = (__hip_bfloat16*)(ws + WS_XT_OFF);
    __hip_bfloat16* hb0 = (__hip_bfloat16*)(ws + WS_HT_OFF);
    __hip_bfloat16* hb1 = (__hip_bfloat16*)(ws + WS_HT_OFF + 1048576);
    unsigned int*   cnt = (unsigned int*)(ws + WS_CNT_OFF);

    prep_wfrag<<<240, 256, 0, stream>>>(Wc, wf);
    prep_xt<<<dim3(B_ * T_, 4), 256, 0, stream>>>(x, xt);
    init_cnt<<<1, 256, 0, stream>>>(cnt);

    lstm_persistent<<<dim3(8, 2, B_), 256, 0, stream>>>(xt, wf, bc, hb0, hb1, out, cnt);
}

// Round 7
// 791.528 us; speedup vs baseline: 2.3342x; 1.0110x over previous
//
#include <hip/hip_runtime.h>
#include <hip/hip_bf16.h>
#include <math.h>

#define B_ 16
#define T_ 64
#define C_ 64
#define W_ 256
#define H_ 128
#define CH_ 192   // C_ + H_
#define K_ 5

#define OUT_SEQ_ELEMS ((size_t)B_ * T_ * H_ * W_)            // 33,554,432
#define OUT_H_OFF     OUT_SEQ_ELEMS                          // final h [B,H,W]
#define OUT_C_OFF     (OUT_SEQ_ELEMS + (size_t)B_ * H_ * W_) // final c [B,H,W]

// ---- workspace layout (bytes) ----
#define WS_WF_OFF  0                              // Wfrag bf16: 983040 B
#define WS_XT_OFF  (983040)                       // xT bf16 [B][T][W][C] = 33554432 B
#define WS_HT_OFF  (WS_XT_OFF + 33554432)         // 2 x hT bf16 [B][W][H] = 1 MB each
#define WS_CNT_OFF (WS_HT_OFF + 2 * 1048576)      // 16 padded counters (64B stride)

typedef __attribute__((ext_vector_type(8))) short bf16x8;
typedef __attribute__((ext_vector_type(4))) float f32x4;
typedef __attribute__((ext_vector_type(4))) unsigned int u32x4;

__device__ __forceinline__ float sigmoid_f(float x) {
    return 1.0f / (1.0f + __expf(-x));
}
__device__ __forceinline__ float tanh_f(float x) {
    return 1.0f - 2.0f / (__expf(2.0f * x) + 1.0f);
}

// ---------- prep: weights -> MFMA fragment-major bf16 ----------
__global__ __launch_bounds__(256)
void prep_wfrag(const float* __restrict__ Wc, __hip_bfloat16* __restrict__ wf) {
    int idx = blockIdx.x * 256 + threadIdx.x;
    if (idx >= 960 * 64) return;
    int lane  = idx & 63;
    int f     = idx >> 6;
    int chunk = f % 6;
    int ktap  = (f / 6) % 5;
    int g     = (f / 30) % 4;
    int ht    = f / 120;
    int chan  = g * 128 + ht * 16 + (lane & 15);
    int ci0   = chunk * 32 + 8 * (lane >> 4);
    __hip_bfloat16 tmp[8];
#pragma unroll
    for (int j = 0; j < 8; ++j)
        tmp[j] = __float2bfloat16(Wc[((size_t)chan * CH_ + (ci0 + j)) * K_ + ktap]);
    *reinterpret_cast<u32x4*>(&wf[(size_t)idx * 8]) = *reinterpret_cast<const u32x4*>(tmp);
}

// ---------- prep: x [B,T,C,W] f32 -> xT [B,T,W,C] bf16 ----------
__global__ __launch_bounds__(256)
void prep_xt(const float* __restrict__ x, __hip_bfloat16* __restrict__ xt) {
    __shared__ float tile[64][65];
    int bt = blockIdx.x;
    int w0 = blockIdx.y * 64;
    const float* src = x + (size_t)bt * C_ * W_ + w0;
#pragma unroll
    for (int i = 0; i < 16; ++i) {
        int idx = i * 256 + threadIdx.x;
        int ci = idx >> 6, wr = idx & 63;
        tile[ci][wr] = src[(size_t)ci * W_ + wr];
    }
    __syncthreads();
    __hip_bfloat16* dst = xt + ((size_t)bt * W_ + w0) * C_;
#pragma unroll
    for (int i = 0; i < 8; ++i) {
        int idx = i * 256 + threadIdx.x;
        int wr = idx >> 5, cp = (idx & 31) * 2;
        __hip_bfloat16 a = __float2bfloat16(tile[cp][wr]);
        __hip_bfloat16 b = __float2bfloat16(tile[cp + 1][wr]);
        ushort2 v;
        v.x = *reinterpret_cast<unsigned short*>(&a);
        v.y = *reinterpret_cast<unsigned short*>(&b);
        *reinterpret_cast<ushort2*>(&dst[(size_t)wr * C_ + cp]) = v;
    }
}

__global__ void init_cnt(unsigned int* cnt) {
    if (threadIdx.x < 16 * 16) cnt[threadIdx.x] = 0;
}

// ---------- persistent kernel: all 64 steps ----------
// 256 blocks, 1/CU. h/counter traffic via coherent LLC (sc1 dwordx4).
// This round: (a) h sc1 loads issued BEFORE the x-only MFMA chunks (c=0,1),
// vmcnt-drained after -- LLC latency hides under x-compute; (b) gbuf/hbf get
// dedicated LDS regions (no combT alias) -> one less barrier, waves write
// gbuf right after their own MFMAs.
#define PITCH_B 384   // bytes per combT row (192 ci * 2B), XOR-swizzled
#define NROWS   132   // 128 positions + 4 halo
#define GBUF_OFF 50688            // f32 [4][16][128] = 32768 B
#define HBF_OFF  (50688 + 32768)  // bf16 [128][24]   = 6144 B  (total 89600)

__global__ __launch_bounds__(256, 1)
void lstm_persistent(const __hip_bfloat16* __restrict__ xt,
                     const __hip_bfloat16* __restrict__ wf,
                     const float* __restrict__ bc,
                     __hip_bfloat16* __restrict__ hbuf0,
                     __hip_bfloat16* __restrict__ hbuf1,
                     float* __restrict__ out,
                     unsigned int* __restrict__ cnt)
{
    __shared__ char lds[89600];
    const int ht   = blockIdx.x;         // 0..7
    const int wseg = blockIdx.y;         // 0..1
    const int b    = blockIdx.z;         // 0..15
    const int tid  = threadIdx.x;
    const int lane = tid & 63;
    const int g    = tid >> 6;           // wave id == gate
    const int l15  = lane & 15;
    const int lg   = lane >> 4;
    unsigned int* cntb = cnt + b * 16;

    // ---- persistent state: weights in VGPRs, bias, c-state ----
    bf16x8 wreg[30];
    {
        const __hip_bfloat16* wfbase = wf + (size_t)(ht * 4 + g) * 30 * 512 + (size_t)lane * 8;
#pragma unroll
        for (int f = 0; f < 30; ++f)
            wreg[f] = *reinterpret_cast<const bf16x8*>(wfbase + (size_t)f * 512);
    }
    float bias[4];
    {
        int chanbase = g * 128 + ht * 16 + (lg << 2);
#pragma unroll
        for (int r = 0; r < 4; ++r) bias[r] = bc[chanbase + r];
    }
    float cstate[8];
#pragma unroll
    for (int i = 0; i < 8; ++i) cstate[i] = 0.0f;

    const int wbase = wseg * 128 - 2;
    const int cib = 16 * lg;

    // ---- zero combT h-columns once (t==0 sees zero h) ----
    for (int idx = tid; idx < NROWS * 16; idx += 256) {
        int wrel = idx >> 4;
        int c16  = (idx & 15) + 8;
        int byteoff = wrel * PITCH_B + ((c16 * 16) ^ ((wrel & 7) << 4));
        u32x4 z = {0u, 0u, 0u, 0u};
        *reinterpret_cast<u32x4*>(lds + byteoff) = z;
    }

    for (int t = 0; t < T_; ++t) {
        const __hip_bfloat16* xrow = xt + ((size_t)(b * T_ + t) * W_) * C_;
        const __hip_bfloat16* hrow = ((t & 1) ? hbuf0 : hbuf1) + (size_t)b * W_ * H_;
        __hip_bfloat16* hout = ((t & 1) ? hbuf1 : hbuf0);

        // ---- stage x half of combT (overlaps the wait below) ----
        for (int idx = tid; idx < NROWS * 8; idx += 256) {
            int wrel = idx >> 3;
            int c16  = idx & 7;
            int w = wbase + wrel;
            u32x4 v = {0u, 0u, 0u, 0u};
            if (w >= 0 && w < W_)
                v = *reinterpret_cast<const u32x4*>(xrow + (size_t)w * C_ + c16 * 8);
            int byteoff = wrel * PITCH_B + ((c16 * 16) ^ ((wrel & 7) << 4));
            *reinterpret_cast<u32x4*>(lds + byteoff) = v;
        }

        // ---- wait for h(t-1) from all 16 blocks of this batch ----
        if (t > 0) {
            if (tid == 0) {
                unsigned int target = 16u * (unsigned int)t;
                while (__hip_atomic_load(cntb, __ATOMIC_RELAXED, __HIP_MEMORY_SCOPE_AGENT) < target)
                    __builtin_amdgcn_s_sleep(1);
            }
        }
        __syncthreads();                       // B1: x staged + h ready
        __atomic_signal_fence(__ATOMIC_SEQ_CST);

        // ---- issue h sc1 loads (no wait yet) ----
        u32x4 hv[8];
        u32x4 hv8 = {0u, 0u, 0u, 0u};
        if (t > 0) {
            const u32x4 zz = {0u, 0u, 0u, 0u};
#pragma unroll
            for (int i = 0; i < 8; ++i) {
                int idx  = i * 256 + tid;
                int wrel = idx >> 4;
                int c16  = idx & 15;
                int w = wbase + wrel;
                hv[i] = zz;
                if (w >= 0 && w < W_) {
                    const __hip_bfloat16* hp = hrow + (size_t)w * H_ + c16 * 8;
                    asm volatile("global_load_dwordx4 %0, %1, off sc1"
                                 : "+v"(hv[i]) : "v"(hp));
                }
            }
            if (tid < 64) {
                int idx  = 2048 + tid;
                int wrel = idx >> 4;
                int c16  = idx & 15;
                int w = wbase + wrel;
                if (w >= 0 && w < W_) {
                    const __hip_bfloat16* hp = hrow + (size_t)w * H_ + c16 * 8;
                    asm volatile("global_load_dwordx4 %0, %1, off sc1"
                                 : "+v"(hv8) : "v"(hp));
                }
            }
        }

        // ---- acc init + x-only MFMA (chunks 0,1) while h loads fly ----
        f32x4 acc[8];
#pragma unroll
        for (int nf = 0; nf < 8; ++nf) {
            acc[nf][0] = bias[0]; acc[nf][1] = bias[1];
            acc[nf][2] = bias[2]; acc[nf][3] = bias[3];
        }
#pragma unroll
        for (int c = 0; c < 2; ++c) {
#pragma unroll
            for (int k = 0; k < K_; ++k) {
                bf16x8 afrag = wreg[k * 6 + c];
#pragma unroll
                for (int nf = 0; nf < 8; ++nf) {
                    int wrel = nf * 16 + l15 + k;
                    int byteoff = wrel * PITCH_B + ((c * 64 + cib) ^ ((wrel & 7) << 4));
                    bf16x8 bfrag = *reinterpret_cast<const bf16x8*>(lds + byteoff);
                    acc[nf] = __builtin_amdgcn_mfma_f32_16x16x32_bf16(afrag, bfrag, acc[nf], 0, 0, 0);
                }
            }
        }

        // ---- drain h loads, write h into combT h-columns ----
        if (t > 0) {
            asm volatile("s_waitcnt vmcnt(0)" ::: "memory");
            __builtin_amdgcn_sched_barrier(0);
#pragma unroll
            for (int i = 0; i < 8; ++i) {
                int idx  = i * 256 + tid;
                int wrel = idx >> 4;
                int c16  = (idx & 15) + 8;
                int byteoff = wrel * PITCH_B + ((c16 * 16) ^ ((wrel & 7) << 4));
                *reinterpret_cast<u32x4*>(lds + byteoff) = hv[i];
            }
            if (tid < 64) {
                int idx  = 2048 + tid;
                int wrel = idx >> 4;
                int c16  = (idx & 15) + 8;
                int byteoff = wrel * PITCH_B + ((c16 * 16) ^ ((wrel & 7) << 4));
                *reinterpret_cast<u32x4*>(lds + byteoff) = hv8;
            }
        }
        __syncthreads();                       // B2: h columns ready

        // ---- h MFMA (chunks 2..5) ----
#pragma unroll
        for (int c = 2; c < 6; ++c) {
#pragma unroll
            for (int k = 0; k < K_; ++k) {
                bf16x8 afrag = wreg[k * 6 + c];
#pragma unroll
                for (int nf = 0; nf < 8; ++nf) {
                    int wrel = nf * 16 + l15 + k;
                    int byteoff = wrel * PITCH_B + ((c * 64 + cib) ^ ((wrel & 7) << 4));
                    bf16x8 bfrag = *reinterpret_cast<const bf16x8*>(lds + byteoff);
                    acc[nf] = __builtin_amdgcn_mfma_f32_16x16x32_bf16(afrag, bfrag, acc[nf], 0, 0, 0);
                }
            }
        }

        // ---- gates -> dedicated gbuf (no barrier before: own region) ----
        float* gbuf = reinterpret_cast<float*>(lds + GBUF_OFF);   // [4][16][128]
        {
            int rowb = lg << 2;
#pragma unroll
            for (int nf = 0; nf < 8; ++nf)
#pragma unroll
                for (int r = 0; r < 4; ++r)
                    gbuf[(g * 16 + rowb + r) * 128 + nf * 16 + l15] = acc[nf][r];
        }
        __syncthreads();                       // B3: gbuf complete

        // ---- gating: c + h in registers; bf16 h -> hbf for publish ----
        __hip_bfloat16* hbf = reinterpret_cast<__hip_bfloat16*>(lds + HBF_OFF); // [128][24]
        float hn_r[8];
#pragma unroll
        for (int i = 0; i < 8; ++i) {
            int idx  = i * 256 + tid;
            int chan = idx >> 7;
            int pos  = idx & 127;
            float vi = gbuf[(0 * 16 + chan) * 128 + pos];
            float vf = gbuf[(1 * 16 + chan) * 128 + pos];
            float vo = gbuf[(2 * 16 + chan) * 128 + pos];
            float vg = gbuf[(3 * 16 + chan) * 128 + pos];
            float ii = sigmoid_f(vi), ff = sigmoid_f(vf), oo = sigmoid_f(vo), gg = tanh_f(vg);
            float cn = ff * cstate[i] + ii * gg;
            cstate[i] = cn;
            float hn = oo * tanh_f(cn);
            hn_r[i] = hn;
            hbf[pos * 24 + chan] = __float2bfloat16(hn);
        }
        __syncthreads();                       // B4: hbf complete

        // ---- publish hT (dwordx4 sc1 -> LLC), then signal ----
        {
            int w = tid >> 1, grp = tid & 1;
            u32x4 v = *reinterpret_cast<const u32x4*>(lds + HBF_OFF + w * 48 + grp * 16);
            __hip_bfloat16* hp = hout + ((size_t)b * W_ + wseg * 128 + w) * H_ + ht * 16 + grp * 8;
            asm volatile("global_store_dwordx4 %0, %1, off sc1" :: "v"(hp), "v"(v) : "memory");
        }
        asm volatile("s_waitcnt vmcnt(0)" ::: "memory");
        __syncthreads();                       // B5: all stores landed
        if (tid == 0)
            __hip_atomic_fetch_add(cntb, 1u, __ATOMIC_RELAXED, __HIP_MEMORY_SCOPE_AGENT);

        // ---- deferred (off critical path): fp32 out writes ----
        float* hw = out + ((size_t)(b * T_ + t) * H_ + ht * 16) * W_ + wseg * 128;
#pragma unroll
        for (int i = 0; i < 8; ++i) {
            int idx  = i * 256 + tid;
            int chan = idx >> 7;
            int pos  = idx & 127;
            hw[(size_t)chan * W_ + pos] = hn_r[i];
        }
        if (t == T_ - 1) {
#pragma unroll
            for (int i = 0; i < 8; ++i) {
                int idx  = i * 256 + tid;
                int chan = idx >> 7;
                int pos  = idx & 127;
                out[OUT_H_OFF + ((size_t)b * H_ + ht * 16 + chan) * W_ + wseg * 128 + pos] = hn_r[i];
                out[OUT_C_OFF + ((size_t)b * H_ + ht * 16 + chan) * W_ + wseg * 128 + pos] = cstate[i];
            }
        }
    }
}

extern "C" void kernel_launch(void* const* d_in, const int* in_sizes, int n_in,
                              void* d_out, int out_size, void* d_ws, size_t ws_size,
                              hipStream_t stream)
{
    const float* x  = (const float*)d_in[0];
    const float* Wc = (const float*)d_in[1];
    const float* bc = (const float*)d_in[2];
    float* out = (float*)d_out;
    char*  ws  = (char*)d_ws;

    __hip_bfloat16* wf  = (__hip_bfloat16*)(ws + WS_WF_OFF);
    __hip_bfloat16* xt  = (__hip_bfloat16*)(ws + WS_XT_OFF);
    __hip_bfloat16* hb0 = (__hip_bfloat16*)(ws + WS_HT_OFF);
    __hip_bfloat16* hb1 = (__hip_bfloat16*)(ws + WS_HT_OFF + 1048576);
    unsigned int*   cnt = (unsigned int*)(ws + WS_CNT_OFF);

    prep_wfrag<<<240, 256, 0, stream>>>(Wc, wf);
    prep_xt<<<dim3(B_ * T_, 4), 256, 0, stream>>>(x, xt);
    init_cnt<<<1, 256, 0, stream>>>(cnt);

    lstm_persistent<<<dim3(8, 2, B_), 256, 0, stream>>>(xt, wf, bc, hb0, hb1, out, cnt);
}